// Round 6
// baseline (617.234 us; speedup 1.0000x reference)
//
#include <hip/hip_runtime.h>
#include <hip/hip_fp16.h>

#define NUM_USERS 100000
#define NN        200000          // N = users + items
#define DD        64
#define EE        3200000
#define SCAN_CHUNK 2048
#define NB_SCAN   98              // covers up to 200704 elements (>= NN+1)

typedef _Float16 half8 __attribute__((ext_vector_type(8)));
typedef _Float16 half4 __attribute__((ext_vector_type(4)));
typedef float    f32x4 __attribute__((ext_vector_type(4)));

// ---------------------------------------------------------------------------
// Pass 1: per-node histogram via global atomics (200k counters, ~16 hits
// each -> negligible contention). Replaces seg_hist + bucket-level machinery.
// ---------------------------------------------------------------------------
__global__ __launch_bounds__(256) void node_hist_kernel(
    const int* __restrict__ ei, int* __restrict__ cnt)
{
    const int i = blockIdx.x * 256 + threadIdx.x;   // E/4 threads
    const int4 d = ((const int4*)(ei + EE))[i];
    atomicAdd(&cnt[d.x], 1);
    atomicAdd(&cnt[d.y], 1);
    atomicAdd(&cnt[d.z], 1);
    atomicAdd(&cnt[d.w], 1);
}

// ---------------------------------------------------------------------------
// 3-phase exclusive scan over node counts (len = NN).
// scan_write also emits the cursor copy and the row_ptr[NN]=EE tail.
// ---------------------------------------------------------------------------
__global__ __launch_bounds__(256) void scan_partials_kernel(
    const int* __restrict__ counts, int* __restrict__ bsum, int len)
{
    __shared__ int s[256];
    const int t = threadIdx.x;
    int sum = 0;
    for (int i = t; i < SCAN_CHUNK; i += 256) {
        const int idx = blockIdx.x * SCAN_CHUNK + i;
        sum += (idx < len) ? counts[idx] : 0;
    }
    s[t] = sum; __syncthreads();
    for (int off = 128; off > 0; off >>= 1) {
        if (t < off) s[t] += s[t + off];
        __syncthreads();
    }
    if (t == 0) bsum[blockIdx.x] = s[0];
}

__global__ __launch_bounds__(128) void scan_top_kernel(int* __restrict__ bsum, int nb)
{
    __shared__ int s[128];
    const int t = threadIdx.x;
    const int v = (t < nb) ? bsum[t] : 0;
    s[t] = v; __syncthreads();
    for (int off = 1; off < 128; off <<= 1) {
        int add = (t >= off) ? s[t - off] : 0;
        __syncthreads();
        s[t] += add;
        __syncthreads();
    }
    if (t < nb) bsum[t] = s[t] - v;   // exclusive
}

__global__ __launch_bounds__(256) void scan_write_kernel(
    const int* __restrict__ counts, const int* __restrict__ bsum,
    int* __restrict__ row_ptr, int* __restrict__ cur, int len)
{
    __shared__ int s[256];
    const int t    = threadIdx.x;
    const int base = blockIdx.x * SCAN_CHUNK + t * 8;
    int c[8], ex[8], run = 0;
#pragma unroll
    for (int j = 0; j < 8; ++j) {
        const int idx = base + j;
        c[j] = (idx < len) ? counts[idx] : 0;
        ex[j] = run; run += c[j];
    }
    s[t] = run; __syncthreads();
    for (int off = 1; off < 256; off <<= 1) {
        int add = (t >= off) ? s[t - off] : 0;
        __syncthreads();
        s[t] += add;
        __syncthreads();
    }
    const int thread_base = bsum[blockIdx.x] + s[t] - run;
#pragma unroll
    for (int j = 0; j < 8; ++j) {
        const int idx = base + j;
        if (idx < len) {
            const int v = thread_base + ex[j];
            row_ptr[idx] = v;
            cur[idx]     = v;
        }
    }
    // tail: total == EE lands in the last block's inclusive sum
    if (blockIdx.x == NB_SCAN - 1 && t == 255)
        row_ptr[len] = bsum[blockIdx.x] + s[255];
}

// ---------------------------------------------------------------------------
// Pass 2: direct scatter into final row-grouped order.
// Record: x = src*128 (byte offset into fp16 table), y = w bits.
// Order within a row is nondeterministic (atomic), but aggregation is fp32 —
// reorder error ~1e-6, far below tolerance.
// ---------------------------------------------------------------------------
__global__ __launch_bounds__(256) void scatter_kernel(
    const int* __restrict__ ei, const float* __restrict__ ew,
    int* __restrict__ cur, int2* __restrict__ edges)
{
    const int i = blockIdx.x * 256 + threadIdx.x;   // E threads
    const int   src = ei[i];
    const int   dst = ei[EE + i];
    const float w   = ew[i];
    const int pos = atomicAdd(&cur[dst], 1);
    edges[pos] = make_int2(src << 7, __float_as_int(w));
}

// ---------------------------------------------------------------------------
// fp32 embeddings -> fp16 gather table xh [N][64]
// ---------------------------------------------------------------------------
__global__ __launch_bounds__(256) void convert_x_kernel(
    const float* __restrict__ xu, const float* __restrict__ xi,
    _Float16* __restrict__ xh)
{
    const int i = blockIdx.x * 256 + threadIdx.x;
    if (i >= NN * DD / 4) return;
    const float4 v = (i < NUM_USERS * DD / 4)
                       ? ((const float4*)xu)[i]
                       : ((const float4*)xi)[i - NUM_USERS * DD / 4];
    half4 o; o[0] = (_Float16)v.x; o[1] = (_Float16)v.y;
             o[2] = (_Float16)v.z; o[3] = (_Float16)v.w;
    ((half4*)xh)[i] = o;
}

// W [k][n] fp32 -> Wt [n][k] fp16
__global__ __launch_bounds__(256) void convert_w_kernel(
    const float* __restrict__ W1, const float* __restrict__ W2,
    _Float16* __restrict__ Wt)
{
    const int idx = blockIdx.x * 256 + threadIdx.x;
    if (idx >= 2 * DD * DD) return;
    const int mat = idx >> 12, rem = idx & 4095, k = rem >> 6, n = rem & 63;
    const float* W = mat ? W2 : W1;
    Wt[mat * DD * DD + n * DD + k] = (_Float16)W[k * DD + n];
}

// ---------------------------------------------------------------------------
// Aggregation (v3, proven 73.5 us): one wave per FOUR adjacent rows,
// lane d = dim d. 4 independent streams x 4-edge unroll -> 16 gathers in
// flight. Row bounds via readfirstlane -> records are scalar s_loads.
// All loads plain cached.
// ---------------------------------------------------------------------------
__global__ __launch_bounds__(256) void aggregate_kernel(
    const int2* __restrict__ edges, const int* __restrict__ row_ptr,
    const _Float16* __restrict__ xh, _Float16* __restrict__ u)
{
    const int wave = (blockIdx.x * 256 + threadIdx.x) >> 6;  // 0..49999
    const int lane = threadIdx.x & 63;
    const unsigned lane2 = lane * 2;
    const int nbase = wave * 4;
    const char* xb = (const char*)xh;

    int bnd[5];
#pragma unroll
    for (int k = 0; k < 5; ++k)
        bnd[k] = __builtin_amdgcn_readfirstlane(row_ptr[nbase + k]);

    float acc[4];
#pragma unroll
    for (int k = 0; k < 4; ++k)
        acc[k] = (float)*(const _Float16*)(xb + ((unsigned)(nbase + k) << 7) + lane2);

    int e0 = bnd[0], e1 = bnd[1], e2 = bnd[2], e3 = bnd[3];
    const int f0 = bnd[1], f1 = bnd[2], f2 = bnd[3], f3 = bnd[4];

    // ---- steady state: 16 gathers in flight from 4 independent streams ----
    while ((e0 + 4 <= f0) && (e1 + 4 <= f1) && (e2 + 4 <= f2) && (e3 + 4 <= f3)) {
        const int2 a0 = edges[e0 + 0], a1 = edges[e0 + 1];
        const int2 a2 = edges[e0 + 2], a3 = edges[e0 + 3];
        const int2 b0 = edges[e1 + 0], b1 = edges[e1 + 1];
        const int2 b2 = edges[e1 + 2], b3 = edges[e1 + 3];
        const int2 c0 = edges[e2 + 0], c1 = edges[e2 + 1];
        const int2 c2 = edges[e2 + 2], c3 = edges[e2 + 3];
        const int2 d0 = edges[e3 + 0], d1 = edges[e3 + 1];
        const int2 d2 = edges[e3 + 2], d3 = edges[e3 + 3];

        const float va0 = (float)*(const _Float16*)(xb + (unsigned)a0.x + lane2);
        const float va1 = (float)*(const _Float16*)(xb + (unsigned)a1.x + lane2);
        const float va2 = (float)*(const _Float16*)(xb + (unsigned)a2.x + lane2);
        const float va3 = (float)*(const _Float16*)(xb + (unsigned)a3.x + lane2);
        const float vb0 = (float)*(const _Float16*)(xb + (unsigned)b0.x + lane2);
        const float vb1 = (float)*(const _Float16*)(xb + (unsigned)b1.x + lane2);
        const float vb2 = (float)*(const _Float16*)(xb + (unsigned)b2.x + lane2);
        const float vb3 = (float)*(const _Float16*)(xb + (unsigned)b3.x + lane2);
        const float vc0 = (float)*(const _Float16*)(xb + (unsigned)c0.x + lane2);
        const float vc1 = (float)*(const _Float16*)(xb + (unsigned)c1.x + lane2);
        const float vc2 = (float)*(const _Float16*)(xb + (unsigned)c2.x + lane2);
        const float vc3 = (float)*(const _Float16*)(xb + (unsigned)c3.x + lane2);
        const float vd0 = (float)*(const _Float16*)(xb + (unsigned)d0.x + lane2);
        const float vd1 = (float)*(const _Float16*)(xb + (unsigned)d1.x + lane2);
        const float vd2 = (float)*(const _Float16*)(xb + (unsigned)d2.x + lane2);
        const float vd3 = (float)*(const _Float16*)(xb + (unsigned)d3.x + lane2);

        acc[0] = fmaf(__int_as_float(a0.y), va0, acc[0]);
        acc[0] = fmaf(__int_as_float(a1.y), va1, acc[0]);
        acc[0] = fmaf(__int_as_float(a2.y), va2, acc[0]);
        acc[0] = fmaf(__int_as_float(a3.y), va3, acc[0]);
        acc[1] = fmaf(__int_as_float(b0.y), vb0, acc[1]);
        acc[1] = fmaf(__int_as_float(b1.y), vb1, acc[1]);
        acc[1] = fmaf(__int_as_float(b2.y), vb2, acc[1]);
        acc[1] = fmaf(__int_as_float(b3.y), vb3, acc[1]);
        acc[2] = fmaf(__int_as_float(c0.y), vc0, acc[2]);
        acc[2] = fmaf(__int_as_float(c1.y), vc1, acc[2]);
        acc[2] = fmaf(__int_as_float(c2.y), vc2, acc[2]);
        acc[2] = fmaf(__int_as_float(c3.y), vc3, acc[2]);
        acc[3] = fmaf(__int_as_float(d0.y), vd0, acc[3]);
        acc[3] = fmaf(__int_as_float(d1.y), vd1, acc[3]);
        acc[3] = fmaf(__int_as_float(d2.y), vd2, acc[3]);
        acc[3] = fmaf(__int_as_float(d3.y), vd3, acc[3]);

        e0 += 4; e1 += 4; e2 += 4; e3 += 4;
    }

    // ---- per-stream drains (4-unroll then scalar) ----
    {
        int e = e0;
        for (; e + 4 <= f0; e += 4) {
            const int2 r0 = edges[e + 0], r1 = edges[e + 1];
            const int2 r2 = edges[e + 2], r3 = edges[e + 3];
            const float v0 = (float)*(const _Float16*)(xb + (unsigned)r0.x + lane2);
            const float v1 = (float)*(const _Float16*)(xb + (unsigned)r1.x + lane2);
            const float v2 = (float)*(const _Float16*)(xb + (unsigned)r2.x + lane2);
            const float v3 = (float)*(const _Float16*)(xb + (unsigned)r3.x + lane2);
            acc[0] = fmaf(__int_as_float(r0.y), v0, acc[0]);
            acc[0] = fmaf(__int_as_float(r1.y), v1, acc[0]);
            acc[0] = fmaf(__int_as_float(r2.y), v2, acc[0]);
            acc[0] = fmaf(__int_as_float(r3.y), v3, acc[0]);
        }
        for (; e < f0; ++e) {
            const int2 p = edges[e];
            acc[0] = fmaf(__int_as_float(p.y),
                          (float)*(const _Float16*)(xb + (unsigned)p.x + lane2), acc[0]);
        }
    }
    {
        int e = e1;
        for (; e + 4 <= f1; e += 4) {
            const int2 r0 = edges[e + 0], r1 = edges[e + 1];
            const int2 r2 = edges[e + 2], r3 = edges[e + 3];
            const float v0 = (float)*(const _Float16*)(xb + (unsigned)r0.x + lane2);
            const float v1 = (float)*(const _Float16*)(xb + (unsigned)r1.x + lane2);
            const float v2 = (float)*(const _Float16*)(xb + (unsigned)r2.x + lane2);
            const float v3 = (float)*(const _Float16*)(xb + (unsigned)r3.x + lane2);
            acc[1] = fmaf(__int_as_float(r0.y), v0, acc[1]);
            acc[1] = fmaf(__int_as_float(r1.y), v1, acc[1]);
            acc[1] = fmaf(__int_as_float(r2.y), v2, acc[1]);
            acc[1] = fmaf(__int_as_float(r3.y), v3, acc[1]);
        }
        for (; e < f1; ++e) {
            const int2 p = edges[e];
            acc[1] = fmaf(__int_as_float(p.y),
                          (float)*(const _Float16*)(xb + (unsigned)p.x + lane2), acc[1]);
        }
    }
    {
        int e = e2;
        for (; e + 4 <= f2; e += 4) {
            const int2 r0 = edges[e + 0], r1 = edges[e + 1];
            const int2 r2 = edges[e + 2], r3 = edges[e + 3];
            const float v0 = (float)*(const _Float16*)(xb + (unsigned)r0.x + lane2);
            const float v1 = (float)*(const _Float16*)(xb + (unsigned)r1.x + lane2);
            const float v2 = (float)*(const _Float16*)(xb + (unsigned)r2.x + lane2);
            const float v3 = (float)*(const _Float16*)(xb + (unsigned)r3.x + lane2);
            acc[2] = fmaf(__int_as_float(r0.y), v0, acc[2]);
            acc[2] = fmaf(__int_as_float(r1.y), v1, acc[2]);
            acc[2] = fmaf(__int_as_float(r2.y), v2, acc[2]);
            acc[2] = fmaf(__int_as_float(r3.y), v3, acc[2]);
        }
        for (; e < f2; ++e) {
            const int2 p = edges[e];
            acc[2] = fmaf(__int_as_float(p.y),
                          (float)*(const _Float16*)(xb + (unsigned)p.x + lane2), acc[2]);
        }
    }
    {
        int e = e3;
        for (; e + 4 <= f3; e += 4) {
            const int2 r0 = edges[e + 0], r1 = edges[e + 1];
            const int2 r2 = edges[e + 2], r3 = edges[e + 3];
            const float v0 = (float)*(const _Float16*)(xb + (unsigned)r0.x + lane2);
            const float v1 = (float)*(const _Float16*)(xb + (unsigned)r1.x + lane2);
            const float v2 = (float)*(const _Float16*)(xb + (unsigned)r2.x + lane2);
            const float v3 = (float)*(const _Float16*)(xb + (unsigned)r3.x + lane2);
            acc[3] = fmaf(__int_as_float(r0.y), v0, acc[3]);
            acc[3] = fmaf(__int_as_float(r1.y), v1, acc[3]);
            acc[3] = fmaf(__int_as_float(r2.y), v2, acc[3]);
            acc[3] = fmaf(__int_as_float(r3.y), v3, acc[3]);
        }
        for (; e < f3; ++e) {
            const int2 p = edges[e];
            acc[3] = fmaf(__int_as_float(p.y),
                          (float)*(const _Float16*)(xb + (unsigned)p.x + lane2), acc[3]);
        }
    }

    char* ub = (char*)u;
#pragma unroll
    for (int k = 0; k < 4; ++k)
        *(_Float16*)(ub + ((unsigned)(nbase + k) << 7) + lane2) = (_Float16)(acc[k] * 0.5f);
}

// ---------------------------------------------------------------------------
// GEMM: out[N,64] = u[N,64] @ W[64,64] + b (unchanged)
// ---------------------------------------------------------------------------
template<bool HALF_OUT>
__global__ __launch_bounds__(256) void gemm64_kernel(
    const _Float16* __restrict__ u, const _Float16* __restrict__ Wt,
    const float* __restrict__ bias, void* __restrict__ outp)
{
    const int wid  = blockIdx.x * 4 + (threadIdx.x >> 6);
    const int lane = threadIdx.x & 63;
    const int m    = lane & 15;
    const int quad = lane >> 4;
    const size_t rowbase = (size_t)wid * 16;

    half8 bf[4][2];
#pragma unroll
    for (int c = 0; c < 4; ++c)
#pragma unroll
        for (int h = 0; h < 2; ++h)
            bf[c][h] = *(const half8*)(Wt + (size_t)(c * 16 + m) * DD + h * 32 + quad * 8);

    const half8 a0 = *(const half8*)(u + (rowbase + m) * DD +  0 + quad * 8);
    const half8 a1 = *(const half8*)(u + (rowbase + m) * DD + 32 + quad * 8);

    f32x4 acc[4];
#pragma unroll
    for (int c = 0; c < 4; ++c) {
        f32x4 z = {0.f, 0.f, 0.f, 0.f};
        z = __builtin_amdgcn_mfma_f32_16x16x32_f16(a0, bf[c][0], z, 0, 0, 0);
        z = __builtin_amdgcn_mfma_f32_16x16x32_f16(a1, bf[c][1], z, 0, 0, 0);
        acc[c] = z;
    }

#pragma unroll
    for (int c = 0; c < 4; ++c) {
        const float bv = bias[c * 16 + m];
#pragma unroll
        for (int r = 0; r < 4; ++r) {
            const size_t row = rowbase + quad * 4 + r;
            const float val = acc[c][r] + bv;
            if (HALF_OUT) ((_Float16*)outp)[row * DD + c * 16 + m] = (_Float16)val;
            else          ((float*)    outp)[row * DD + c * 16 + m] = val;
        }
    }
}

extern "C" void kernel_launch(void* const* d_in, const int* in_sizes, int n_in,
                              void* d_out, int out_size, void* d_ws, size_t ws_size,
                              hipStream_t stream) {
    const int*   edge_index  = (const int*)  d_in[0];
    const float* edge_weight = (const float*)d_in[1];
    const float* user_emb    = (const float*)d_in[2];
    const float* item_emb    = (const float*)d_in[3];
    const float* W1          = (const float*)d_in[4];
    const float* b1          = (const float*)d_in[5];
    const float* W2          = (const float*)d_in[6];
    const float* b2          = (const float*)d_in[7];
    float*       out         = (float*)d_out;

    // Workspace layout:
    char* ws = (char*)d_ws;
    _Float16* xh        = (_Float16*)(ws);               // 25,600,000 B (h1 aliases after layer 1)
    _Float16* u         = (_Float16*)(ws + 25600000);    // 25,600,000 B
    int2*     edges     = (int2*)    (ws + 51200000);    // 25,600,000 B (row-grouped)
    int*      row_ptr   = (int*)     (ws + 76800000);    //    800,064 B (NN+1 ints)
    int*      cur       = (int*)     (ws + 78400064);    //    800,768 B (scatter cursors)
    int*      node_cnt  = (int*)     (ws + 79200832);    //    800,768 B (histogram)
    int*      bsum      = (int*)     (ws + 80001600);    //        512 B
    _Float16* Wt        = (_Float16*)(ws + 80002112);    //     16,384 B

    const int gemm_blocks = (NN / 16) / 4;               // 3125
    const int agg_blocks  = NN / 16;                     // 12500 (4 nodes/wave, 4 waves/block)

    // ---- build row_ptr + row-grouped edges (2 edge passes total) ----
    hipMemsetAsync(node_cnt, 0, (size_t)NN * sizeof(int), stream);
    node_hist_kernel    <<<EE / 1024, 256, 0, stream>>>(edge_index, node_cnt);
    scan_partials_kernel<<<NB_SCAN,   256, 0, stream>>>(node_cnt, bsum, NN);
    scan_top_kernel     <<<1,         128, 0, stream>>>(bsum, NB_SCAN);
    scan_write_kernel   <<<NB_SCAN,   256, 0, stream>>>(node_cnt, bsum, row_ptr, cur, NN);
    scatter_kernel      <<<EE / 256,  256, 0, stream>>>(edge_index, edge_weight, cur, edges);

    // ---- fp16 conversions ----
    convert_x_kernel<<<(NN * DD / 4 + 255) / 256, 256, 0, stream>>>(user_emb, item_emb, xh);
    convert_w_kernel<<<(2 * DD * DD + 255) / 256, 256, 0, stream>>>(W1, W2, Wt);

    // ---- Layer 1 ----
    aggregate_kernel<<<agg_blocks, 256, 0, stream>>>(edges, row_ptr, xh, u);
    gemm64_kernel<true><<<gemm_blocks, 256, 0, stream>>>(u, Wt, b1, (void*)xh);

    // ---- Layer 2 ----
    aggregate_kernel<<<agg_blocks, 256, 0, stream>>>(edges, row_ptr, xh, u);
    gemm64_kernel<false><<<gemm_blocks, 256, 0, stream>>>(u, Wt + DD * DD, b2, (void*)out);
}

// Round 7
// 563.142 us; speedup vs baseline: 1.0961x; 1.0961x over previous
//
#include <hip/hip_runtime.h>
#include <hip/hip_fp16.h>

#define NUM_USERS 100000
#define NN        200000          // N = users + items
#define DD        64
#define EE        3200000
#define SCAN_CHUNK 2048
#define NB_SCAN   98              // covers up to 200704 elements (>= NN+1)

#define KB_   391                 // dst buckets: 512 nodes each (dst >> 9)
#define GSEG  512                 // edge segments for append
#define EPS   (EE / GSEG)         // 6250 edges per segment

typedef _Float16 half8 __attribute__((ext_vector_type(8)));
typedef _Float16 half4 __attribute__((ext_vector_type(4)));
typedef float    f32x4 __attribute__((ext_vector_type(4)));

// ---------------------------------------------------------------------------
// Pass 1: per-node histogram via global atomics (200k counters, ~16 hits
// each -> negligible contention).
// ---------------------------------------------------------------------------
__global__ __launch_bounds__(256) void node_hist_kernel(
    const int* __restrict__ ei, int* __restrict__ cnt)
{
    const int i = blockIdx.x * 256 + threadIdx.x;   // E/4 threads
    const int4 d = ((const int4*)(ei + EE))[i];
    atomicAdd(&cnt[d.x], 1);
    atomicAdd(&cnt[d.y], 1);
    atomicAdd(&cnt[d.z], 1);
    atomicAdd(&cnt[d.w], 1);
}

// ---------------------------------------------------------------------------
// 3-phase exclusive scan over node counts (len = NN) -> row_ptr (+ tail EE).
// ---------------------------------------------------------------------------
__global__ __launch_bounds__(256) void scan_partials_kernel(
    const int* __restrict__ counts, int* __restrict__ bsum, int len)
{
    __shared__ int s[256];
    const int t = threadIdx.x;
    int sum = 0;
    for (int i = t; i < SCAN_CHUNK; i += 256) {
        const int idx = blockIdx.x * SCAN_CHUNK + i;
        sum += (idx < len) ? counts[idx] : 0;
    }
    s[t] = sum; __syncthreads();
    for (int off = 128; off > 0; off >>= 1) {
        if (t < off) s[t] += s[t + off];
        __syncthreads();
    }
    if (t == 0) bsum[blockIdx.x] = s[0];
}

__global__ __launch_bounds__(128) void scan_top_kernel(int* __restrict__ bsum, int nb)
{
    __shared__ int s[128];
    const int t = threadIdx.x;
    const int v = (t < nb) ? bsum[t] : 0;
    s[t] = v; __syncthreads();
    for (int off = 1; off < 128; off <<= 1) {
        int add = (t >= off) ? s[t - off] : 0;
        __syncthreads();
        s[t] += add;
        __syncthreads();
    }
    if (t < nb) bsum[t] = s[t] - v;   // exclusive
}

__global__ __launch_bounds__(256) void scan_write_kernel(
    const int* __restrict__ counts, const int* __restrict__ bsum,
    int* __restrict__ row_ptr, int len)
{
    __shared__ int s[256];
    const int t    = threadIdx.x;
    const int base = blockIdx.x * SCAN_CHUNK + t * 8;
    int c[8], ex[8], run = 0;
#pragma unroll
    for (int j = 0; j < 8; ++j) {
        const int idx = base + j;
        c[j] = (idx < len) ? counts[idx] : 0;
        ex[j] = run; run += c[j];
    }
    s[t] = run; __syncthreads();
    for (int off = 1; off < 256; off <<= 1) {
        int add = (t >= off) ? s[t - off] : 0;
        __syncthreads();
        s[t] += add;
        __syncthreads();
    }
    const int thread_base = bsum[blockIdx.x] + s[t] - run;
#pragma unroll
    for (int j = 0; j < 8; ++j) {
        const int idx = base + j;
        if (idx < len) row_ptr[idx] = thread_base + ex[j];
    }
    if (blockIdx.x == NB_SCAN - 1 && t == 255)
        row_ptr[len] = bsum[blockIdx.x] + s[255];   // == EE
}

// bucket bases: bucket_cur[k] = row_ptr[k*512]
__global__ __launch_bounds__(256) void init_bcur_kernel(
    const int* __restrict__ row_ptr, int* __restrict__ bcur)
{
    const int k = blockIdx.x * 256 + threadIdx.x;
    if (k < KB_) bcur[k] = row_ptr[k << 9];
}

// ---------------------------------------------------------------------------
// Pass 2a: bucket append with write locality. Per-block LDS histogram over
// 391 buckets -> ONE global atomic per (block,bucket) reserves a contiguous
// run in the bucket's final region -> writes are ~16-edge contiguous runs.
// Record: x = src | dst_local<<18, y = w bits.
// ---------------------------------------------------------------------------
__global__ __launch_bounds__(256) void bucket_append_kernel(
    const int* __restrict__ ei, const float* __restrict__ ew,
    int* __restrict__ bcur, int2* __restrict__ etmp)
{
    __shared__ int h[KB_];
    const int s = blockIdx.x;
    const int t = threadIdx.x;
    for (int k = t; k < KB_; k += 256) h[k] = 0;
    __syncthreads();
    const int base = s * EPS;
    // count pass (dst only; re-read is L2-warm)
    for (int i = t; i < EPS; i += 256) {
        const int dst = ei[EE + base + i];
        atomicAdd(&h[dst >> 9], 1);
    }
    __syncthreads();
    // reserve contiguous runs; overwrite h with the block's frontier
    for (int k = t; k < KB_; k += 256) {
        const int c = h[k];
        h[k] = c > 0 ? atomicAdd(&bcur[k], c) : 0;
    }
    __syncthreads();
    // write pass
    for (int i = t; i < EPS; i += 256) {
        const int e   = base + i;
        const int   src = ei[e];
        const int   dst = ei[EE + e];
        const float w   = ew[e];
        const int k  = dst >> 9;
        const int dl = dst & 511;
        const int pos = atomicAdd(&h[k], 1);     // LDS frontier
        etmp[pos] = make_int2(src | (dl << 18), __float_as_int(w));
    }
}

// ---------------------------------------------------------------------------
// Pass 2b: exact row placement within each bucket. Cursors come straight
// from row_ptr (no internal count/scan). Reads its etmp range once; writes
// stay inside the bucket's 64KB window.
// Output record: x = src*128 (byte offset into fp16 table), y = w bits.
// ---------------------------------------------------------------------------
__global__ __launch_bounds__(256) void bucket_place_kernel(
    const int2* __restrict__ etmp, const int* __restrict__ row_ptr,
    int2* __restrict__ edges)
{
    __shared__ int cur[512];
    const int k = blockIdx.x;
    const int t = threadIdx.x;
    const int node0 = k << 9;
#pragma unroll
    for (int j = t; j < 512; j += 256) {
        const int n = node0 + j;
        cur[j] = (n < NN) ? row_ptr[n] : EE;
    }
    __syncthreads();
    const int beg  = row_ptr[node0];
    const int endn = (node0 + 512 < NN) ? (node0 + 512) : NN;
    const int end  = row_ptr[endn];
    for (int e = beg + t; e < end; e += 256) {
        const int2 r  = etmp[e];
        const int  dl = ((unsigned)r.x) >> 18;
        const int  pos = atomicAdd(&cur[dl], 1);  // LDS atomic
        edges[pos] = make_int2((r.x & 0x3FFFF) << 7, r.y);   // src byte-offset
    }
}

// ---------------------------------------------------------------------------
// fp32 embeddings -> fp16 gather table xh [N][64]
// ---------------------------------------------------------------------------
__global__ __launch_bounds__(256) void convert_x_kernel(
    const float* __restrict__ xu, const float* __restrict__ xi,
    _Float16* __restrict__ xh)
{
    const int i = blockIdx.x * 256 + threadIdx.x;
    if (i >= NN * DD / 4) return;
    const float4 v = (i < NUM_USERS * DD / 4)
                       ? ((const float4*)xu)[i]
                       : ((const float4*)xi)[i - NUM_USERS * DD / 4];
    half4 o; o[0] = (_Float16)v.x; o[1] = (_Float16)v.y;
             o[2] = (_Float16)v.z; o[3] = (_Float16)v.w;
    ((half4*)xh)[i] = o;
}

// W [k][n] fp32 -> Wt [n][k] fp16
__global__ __launch_bounds__(256) void convert_w_kernel(
    const float* __restrict__ W1, const float* __restrict__ W2,
    _Float16* __restrict__ Wt)
{
    const int idx = blockIdx.x * 256 + threadIdx.x;
    if (idx >= 2 * DD * DD) return;
    const int mat = idx >> 12, rem = idx & 4095, k = rem >> 6, n = rem & 63;
    const float* W = mat ? W2 : W1;
    Wt[mat * DD * DD + n * DD + k] = (_Float16)W[k * DD + n];
}

// ---------------------------------------------------------------------------
// Aggregation (v3, proven 73.5 us): one wave per FOUR adjacent rows,
// lane d = dim d. 4 independent streams x 4-edge unroll -> 16 gathers in
// flight. Row bounds via readfirstlane -> records are scalar s_loads.
// All loads plain cached.
// ---------------------------------------------------------------------------
__global__ __launch_bounds__(256) void aggregate_kernel(
    const int2* __restrict__ edges, const int* __restrict__ row_ptr,
    const _Float16* __restrict__ xh, _Float16* __restrict__ u)
{
    const int wave = (blockIdx.x * 256 + threadIdx.x) >> 6;  // 0..49999
    const int lane = threadIdx.x & 63;
    const unsigned lane2 = lane * 2;
    const int nbase = wave * 4;
    const char* xb = (const char*)xh;

    int bnd[5];
#pragma unroll
    for (int k = 0; k < 5; ++k)
        bnd[k] = __builtin_amdgcn_readfirstlane(row_ptr[nbase + k]);

    float acc[4];
#pragma unroll
    for (int k = 0; k < 4; ++k)
        acc[k] = (float)*(const _Float16*)(xb + ((unsigned)(nbase + k) << 7) + lane2);

    int e0 = bnd[0], e1 = bnd[1], e2 = bnd[2], e3 = bnd[3];
    const int f0 = bnd[1], f1 = bnd[2], f2 = bnd[3], f3 = bnd[4];

    // ---- steady state: 16 gathers in flight from 4 independent streams ----
    while ((e0 + 4 <= f0) && (e1 + 4 <= f1) && (e2 + 4 <= f2) && (e3 + 4 <= f3)) {
        const int2 a0 = edges[e0 + 0], a1 = edges[e0 + 1];
        const int2 a2 = edges[e0 + 2], a3 = edges[e0 + 3];
        const int2 b0 = edges[e1 + 0], b1 = edges[e1 + 1];
        const int2 b2 = edges[e1 + 2], b3 = edges[e1 + 3];
        const int2 c0 = edges[e2 + 0], c1 = edges[e2 + 1];
        const int2 c2 = edges[e2 + 2], c3 = edges[e2 + 3];
        const int2 d0 = edges[e3 + 0], d1 = edges[e3 + 1];
        const int2 d2 = edges[e3 + 2], d3 = edges[e3 + 3];

        const float va0 = (float)*(const _Float16*)(xb + (unsigned)a0.x + lane2);
        const float va1 = (float)*(const _Float16*)(xb + (unsigned)a1.x + lane2);
        const float va2 = (float)*(const _Float16*)(xb + (unsigned)a2.x + lane2);
        const float va3 = (float)*(const _Float16*)(xb + (unsigned)a3.x + lane2);
        const float vb0 = (float)*(const _Float16*)(xb + (unsigned)b0.x + lane2);
        const float vb1 = (float)*(const _Float16*)(xb + (unsigned)b1.x + lane2);
        const float vb2 = (float)*(const _Float16*)(xb + (unsigned)b2.x + lane2);
        const float vb3 = (float)*(const _Float16*)(xb + (unsigned)b3.x + lane2);
        const float vc0 = (float)*(const _Float16*)(xb + (unsigned)c0.x + lane2);
        const float vc1 = (float)*(const _Float16*)(xb + (unsigned)c1.x + lane2);
        const float vc2 = (float)*(const _Float16*)(xb + (unsigned)c2.x + lane2);
        const float vc3 = (float)*(const _Float16*)(xb + (unsigned)c3.x + lane2);
        const float vd0 = (float)*(const _Float16*)(xb + (unsigned)d0.x + lane2);
        const float vd1 = (float)*(const _Float16*)(xb + (unsigned)d1.x + lane2);
        const float vd2 = (float)*(const _Float16*)(xb + (unsigned)d2.x + lane2);
        const float vd3 = (float)*(const _Float16*)(xb + (unsigned)d3.x + lane2);

        acc[0] = fmaf(__int_as_float(a0.y), va0, acc[0]);
        acc[0] = fmaf(__int_as_float(a1.y), va1, acc[0]);
        acc[0] = fmaf(__int_as_float(a2.y), va2, acc[0]);
        acc[0] = fmaf(__int_as_float(a3.y), va3, acc[0]);
        acc[1] = fmaf(__int_as_float(b0.y), vb0, acc[1]);
        acc[1] = fmaf(__int_as_float(b1.y), vb1, acc[1]);
        acc[1] = fmaf(__int_as_float(b2.y), vb2, acc[1]);
        acc[1] = fmaf(__int_as_float(b3.y), vb3, acc[1]);
        acc[2] = fmaf(__int_as_float(c0.y), vc0, acc[2]);
        acc[2] = fmaf(__int_as_float(c1.y), vc1, acc[2]);
        acc[2] = fmaf(__int_as_float(c2.y), vc2, acc[2]);
        acc[2] = fmaf(__int_as_float(c3.y), vc3, acc[2]);
        acc[3] = fmaf(__int_as_float(d0.y), vd0, acc[3]);
        acc[3] = fmaf(__int_as_float(d1.y), vd1, acc[3]);
        acc[3] = fmaf(__int_as_float(d2.y), vd2, acc[3]);
        acc[3] = fmaf(__int_as_float(d3.y), vd3, acc[3]);

        e0 += 4; e1 += 4; e2 += 4; e3 += 4;
    }

    // ---- per-stream drains (4-unroll then scalar) ----
    {
        int e = e0;
        for (; e + 4 <= f0; e += 4) {
            const int2 r0 = edges[e + 0], r1 = edges[e + 1];
            const int2 r2 = edges[e + 2], r3 = edges[e + 3];
            const float v0 = (float)*(const _Float16*)(xb + (unsigned)r0.x + lane2);
            const float v1 = (float)*(const _Float16*)(xb + (unsigned)r1.x + lane2);
            const float v2 = (float)*(const _Float16*)(xb + (unsigned)r2.x + lane2);
            const float v3 = (float)*(const _Float16*)(xb + (unsigned)r3.x + lane2);
            acc[0] = fmaf(__int_as_float(r0.y), v0, acc[0]);
            acc[0] = fmaf(__int_as_float(r1.y), v1, acc[0]);
            acc[0] = fmaf(__int_as_float(r2.y), v2, acc[0]);
            acc[0] = fmaf(__int_as_float(r3.y), v3, acc[0]);
        }
        for (; e < f0; ++e) {
            const int2 p = edges[e];
            acc[0] = fmaf(__int_as_float(p.y),
                          (float)*(const _Float16*)(xb + (unsigned)p.x + lane2), acc[0]);
        }
    }
    {
        int e = e1;
        for (; e + 4 <= f1; e += 4) {
            const int2 r0 = edges[e + 0], r1 = edges[e + 1];
            const int2 r2 = edges[e + 2], r3 = edges[e + 3];
            const float v0 = (float)*(const _Float16*)(xb + (unsigned)r0.x + lane2);
            const float v1 = (float)*(const _Float16*)(xb + (unsigned)r1.x + lane2);
            const float v2 = (float)*(const _Float16*)(xb + (unsigned)r2.x + lane2);
            const float v3 = (float)*(const _Float16*)(xb + (unsigned)r3.x + lane2);
            acc[1] = fmaf(__int_as_float(r0.y), v0, acc[1]);
            acc[1] = fmaf(__int_as_float(r1.y), v1, acc[1]);
            acc[1] = fmaf(__int_as_float(r2.y), v2, acc[1]);
            acc[1] = fmaf(__int_as_float(r3.y), v3, acc[1]);
        }
        for (; e < f1; ++e) {
            const int2 p = edges[e];
            acc[1] = fmaf(__int_as_float(p.y),
                          (float)*(const _Float16*)(xb + (unsigned)p.x + lane2), acc[1]);
        }
    }
    {
        int e = e2;
        for (; e + 4 <= f2; e += 4) {
            const int2 r0 = edges[e + 0], r1 = edges[e + 1];
            const int2 r2 = edges[e + 2], r3 = edges[e + 3];
            const float v0 = (float)*(const _Float16*)(xb + (unsigned)r0.x + lane2);
            const float v1 = (float)*(const _Float16*)(xb + (unsigned)r1.x + lane2);
            const float v2 = (float)*(const _Float16*)(xb + (unsigned)r2.x + lane2);
            const float v3 = (float)*(const _Float16*)(xb + (unsigned)r3.x + lane2);
            acc[2] = fmaf(__int_as_float(r0.y), v0, acc[2]);
            acc[2] = fmaf(__int_as_float(r1.y), v1, acc[2]);
            acc[2] = fmaf(__int_as_float(r2.y), v2, acc[2]);
            acc[2] = fmaf(__int_as_float(r3.y), v3, acc[2]);
        }
        for (; e < f2; ++e) {
            const int2 p = edges[e];
            acc[2] = fmaf(__int_as_float(p.y),
                          (float)*(const _Float16*)(xb + (unsigned)p.x + lane2), acc[2]);
        }
    }
    {
        int e = e3;
        for (; e + 4 <= f3; e += 4) {
            const int2 r0 = edges[e + 0], r1 = edges[e + 1];
            const int2 r2 = edges[e + 2], r3 = edges[e + 3];
            const float v0 = (float)*(const _Float16*)(xb + (unsigned)r0.x + lane2);
            const float v1 = (float)*(const _Float16*)(xb + (unsigned)r1.x + lane2);
            const float v2 = (float)*(const _Float16*)(xb + (unsigned)r2.x + lane2);
            const float v3 = (float)*(const _Float16*)(xb + (unsigned)r3.x + lane2);
            acc[3] = fmaf(__int_as_float(r0.y), v0, acc[3]);
            acc[3] = fmaf(__int_as_float(r1.y), v1, acc[3]);
            acc[3] = fmaf(__int_as_float(r2.y), v2, acc[3]);
            acc[3] = fmaf(__int_as_float(r3.y), v3, acc[3]);
        }
        for (; e < f3; ++e) {
            const int2 p = edges[e];
            acc[3] = fmaf(__int_as_float(p.y),
                          (float)*(const _Float16*)(xb + (unsigned)p.x + lane2), acc[3]);
        }
    }

    char* ub = (char*)u;
#pragma unroll
    for (int k = 0; k < 4; ++k)
        *(_Float16*)(ub + ((unsigned)(nbase + k) << 7) + lane2) = (_Float16)(acc[k] * 0.5f);
}

// ---------------------------------------------------------------------------
// GEMM: out[N,64] = u[N,64] @ W[64,64] + b (unchanged)
// ---------------------------------------------------------------------------
template<bool HALF_OUT>
__global__ __launch_bounds__(256) void gemm64_kernel(
    const _Float16* __restrict__ u, const _Float16* __restrict__ Wt,
    const float* __restrict__ bias, void* __restrict__ outp)
{
    const int wid  = blockIdx.x * 4 + (threadIdx.x >> 6);
    const int lane = threadIdx.x & 63;
    const int m    = lane & 15;
    const int quad = lane >> 4;
    const size_t rowbase = (size_t)wid * 16;

    half8 bf[4][2];
#pragma unroll
    for (int c = 0; c < 4; ++c)
#pragma unroll
        for (int h = 0; h < 2; ++h)
            bf[c][h] = *(const half8*)(Wt + (size_t)(c * 16 + m) * DD + h * 32 + quad * 8);

    const half8 a0 = *(const half8*)(u + (rowbase + m) * DD +  0 + quad * 8);
    const half8 a1 = *(const half8*)(u + (rowbase + m) * DD + 32 + quad * 8);

    f32x4 acc[4];
#pragma unroll
    for (int c = 0; c < 4; ++c) {
        f32x4 z = {0.f, 0.f, 0.f, 0.f};
        z = __builtin_amdgcn_mfma_f32_16x16x32_f16(a0, bf[c][0], z, 0, 0, 0);
        z = __builtin_amdgcn_mfma_f32_16x16x32_f16(a1, bf[c][1], z, 0, 0, 0);
        acc[c] = z;
    }

#pragma unroll
    for (int c = 0; c < 4; ++c) {
        const float bv = bias[c * 16 + m];
#pragma unroll
        for (int r = 0; r < 4; ++r) {
            const size_t row = rowbase + quad * 4 + r;
            const float val = acc[c][r] + bv;
            if (HALF_OUT) ((_Float16*)outp)[row * DD + c * 16 + m] = (_Float16)val;
            else          ((float*)    outp)[row * DD + c * 16 + m] = val;
        }
    }
}

extern "C" void kernel_launch(void* const* d_in, const int* in_sizes, int n_in,
                              void* d_out, int out_size, void* d_ws, size_t ws_size,
                              hipStream_t stream) {
    const int*   edge_index  = (const int*)  d_in[0];
    const float* edge_weight = (const float*)d_in[1];
    const float* user_emb    = (const float*)d_in[2];
    const float* item_emb    = (const float*)d_in[3];
    const float* W1          = (const float*)d_in[4];
    const float* b1          = (const float*)d_in[5];
    const float* W2          = (const float*)d_in[6];
    const float* b2          = (const float*)d_in[7];
    float*       out         = (float*)d_out;

    // Workspace layout:
    char* ws = (char*)d_ws;
    _Float16* xh        = (_Float16*)(ws);               // 25,600,000 B (h1 aliases after layer 1)
    _Float16* u         = (_Float16*)(ws + 25600000);    // 25,600,000 B — also etmp during build
    int2*     etmp      = (int2*)    (ws + 25600000);    //   (alias of u)
    int2*     edges     = (int2*)    (ws + 51200000);    // 25,600,000 B (row-grouped)
    int*      row_ptr   = (int*)     (ws + 76800000);    //    800,064 B (NN+1 ints)
    int*      node_cnt  = (int*)     (ws + 78400064);    //    800,768 B (histogram)
    int*      bcur      = (int*)     (ws + 79200832);    //      1,600 B (bucket cursors)
    int*      bsum      = (int*)     (ws + 80001600);    //        512 B
    _Float16* Wt        = (_Float16*)(ws + 80002112);    //     16,384 B

    const int gemm_blocks = (NN / 16) / 4;               // 3125
    const int agg_blocks  = NN / 16;                     // 12500 (4 nodes/wave, 4 waves/block)

    // ---- build row_ptr + row-grouped edges ----
    hipMemsetAsync(node_cnt, 0, (size_t)NN * sizeof(int), stream);
    node_hist_kernel    <<<EE / 1024, 256, 0, stream>>>(edge_index, node_cnt);
    scan_partials_kernel<<<NB_SCAN,   256, 0, stream>>>(node_cnt, bsum, NN);
    scan_top_kernel     <<<1,         128, 0, stream>>>(bsum, NB_SCAN);
    scan_write_kernel   <<<NB_SCAN,   256, 0, stream>>>(node_cnt, bsum, row_ptr, NN);
    init_bcur_kernel    <<<2,         256, 0, stream>>>(row_ptr, bcur);
    bucket_append_kernel<<<GSEG,      256, 0, stream>>>(edge_index, edge_weight, bcur, etmp);
    bucket_place_kernel <<<KB_,       256, 0, stream>>>(etmp, row_ptr, edges);

    // ---- fp16 conversions ----
    convert_x_kernel<<<(NN * DD / 4 + 255) / 256, 256, 0, stream>>>(user_emb, item_emb, xh);
    convert_w_kernel<<<(2 * DD * DD + 255) / 256, 256, 0, stream>>>(W1, W2, Wt);

    // ---- Layer 1 ----
    aggregate_kernel<<<agg_blocks, 256, 0, stream>>>(edges, row_ptr, xh, u);
    gemm64_kernel<true><<<gemm_blocks, 256, 0, stream>>>(u, Wt, b1, (void*)xh);

    // ---- Layer 2 ----
    aggregate_kernel<<<agg_blocks, 256, 0, stream>>>(edges, row_ptr, xh, u);
    gemm64_kernel<false><<<gemm_blocks, 256, 0, stream>>>(u, Wt + DD * DD, b2, (void*)out);
}

// Round 8
// 430.919 us; speedup vs baseline: 1.4324x; 1.3068x over previous
//
#include <hip/hip_runtime.h>
#include <hip/hip_fp16.h>

#define NUM_USERS 100000
#define NN        200000          // N = users + items
#define DD        64
#define EE        3200000

#define KB_   391                 // dst buckets: 512 nodes each (dst >> 9)
#define GSEG  512                 // edge segments for append
#define EPS   (EE / GSEG)         // 6250 edges per segment
#define CVX_BLOCKS 12500          // NN*DD/4 / 256
#define CVW_BLOCKS 32             // 2*DD*DD / 256

typedef _Float16 half8 __attribute__((ext_vector_type(8)));
typedef _Float16 half4 __attribute__((ext_vector_type(4)));
typedef float    f32x4 __attribute__((ext_vector_type(4)));

// ---------------------------------------------------------------------------
// K1 (fused): seg-histogram (blocks [0,512)) || convert_x || convert_w.
// counts_seg layout [s][k] (s*KB_+k): hist writes coalesced, K3 reads
// coalesced; K2's strided reads are L2-served.
// No global atomics; no memset dependencies anywhere in the pipeline.
// ---------------------------------------------------------------------------
__global__ __launch_bounds__(256) void prep_kernel(
    const int* __restrict__ ei,
    const float* __restrict__ xu, const float* __restrict__ xi,
    const float* __restrict__ W1, const float* __restrict__ W2,
    int* __restrict__ counts_seg, _Float16* __restrict__ xh,
    _Float16* __restrict__ Wt)
{
    __shared__ int h[KB_];
    const int b = blockIdx.x;
    const int t = threadIdx.x;
    if (b < GSEG) {
        for (int k = t; k < KB_; k += 256) h[k] = 0;
        __syncthreads();
        const int base = b * EPS;
        for (int i = t; i < EPS; i += 256) {
            const int dst = ei[EE + base + i];
            atomicAdd(&h[dst >> 9], 1);        // LDS atomic
        }
        __syncthreads();
        for (int k = t; k < KB_; k += 256)
            counts_seg[b * KB_ + k] = h[k];
    } else if (b < GSEG + CVX_BLOCKS) {
        const int i = (b - GSEG) * 256 + t;    // < NN*DD/4
        const float4 v = (i < NUM_USERS * DD / 4)
                           ? ((const float4*)xu)[i]
                           : ((const float4*)xi)[i - NUM_USERS * DD / 4];
        half4 o; o[0] = (_Float16)v.x; o[1] = (_Float16)v.y;
                 o[2] = (_Float16)v.z; o[3] = (_Float16)v.w;
        ((half4*)xh)[i] = o;
    } else {
        const int idx = (b - GSEG - CVX_BLOCKS) * 256 + t;   // < 2*DD*DD
        const int mat = idx >> 12, rem = idx & 4095, k = rem >> 6, n = rem & 63;
        const float* W = mat ? W2 : W1;
        Wt[mat * DD * DD + n * DD + k] = (_Float16)W[k * DD + n];
    }
}

// ---------------------------------------------------------------------------
// K2: per-bucket exclusive scan across the 512 segments (in place) + btot.
// Block k handles bucket k; thread t covers segments 2t, 2t+1.
// ---------------------------------------------------------------------------
__global__ __launch_bounds__(256) void bscan_kernel(
    int* __restrict__ counts_seg, int* __restrict__ btot)
{
    __shared__ int part[256];
    const int k = blockIdx.x;
    const int t = threadIdx.x;
    const int c0 = counts_seg[(2 * t)     * KB_ + k];
    const int c1 = counts_seg[(2 * t + 1) * KB_ + k];
    const int run = c0 + c1;
    part[t] = run; __syncthreads();
    for (int off = 1; off < 256; off <<= 1) {
        int add = (t >= off) ? part[t - off] : 0;
        __syncthreads();
        part[t] += add;
        __syncthreads();
    }
    const int base = part[t] - run;            // exclusive within bucket
    counts_seg[(2 * t)     * KB_ + k] = base;
    counts_seg[(2 * t + 1) * KB_ + k] = base + c0;
    if (t == 255) btot[k] = part[255];
}

// ---------------------------------------------------------------------------
// K3: append into bucket-grouped etmp. Bucket bases computed in-block by
// scanning btot (391 values) in LDS; frontier = base + rel[s][k].
// Record: x = src | dst_local<<18, y = w bits. LDS atomics only.
// ---------------------------------------------------------------------------
__global__ __launch_bounds__(256) void append_kernel(
    const int* __restrict__ ei, const float* __restrict__ ew,
    const int* __restrict__ counts_seg, const int* __restrict__ btot,
    int2* __restrict__ etmp)
{
    __shared__ int sb[512];
    __shared__ int part[256];
    __shared__ int fr[KB_];
    const int s = blockIdx.x;
    const int t = threadIdx.x;
    for (int j = t; j < 512; j += 256) sb[j] = (j < KB_) ? btot[j] : 0;
    __syncthreads();
    {
        const int c0 = sb[2 * t], c1 = sb[2 * t + 1];
        const int run = c0 + c1;
        part[t] = run; __syncthreads();
        for (int off = 1; off < 256; off <<= 1) {
            int add = (t >= off) ? part[t - off] : 0;
            __syncthreads();
            part[t] += add;
            __syncthreads();
        }
        const int base = part[t] - run;
        sb[2 * t]     = base;                  // exclusive bucket bases
        sb[2 * t + 1] = base + c0;
    }
    __syncthreads();
    for (int k = t; k < KB_; k += 256)
        fr[k] = sb[k] + counts_seg[s * KB_ + k];
    __syncthreads();
    const int base = s * EPS;
    for (int i = t; i < EPS; i += 256) {
        const int e   = base + i;
        const int   src = ei[e];
        const int   dst = ei[EE + e];
        const float w   = ew[e];
        const int k  = dst >> 9;
        const int dl = dst & 511;
        const int pos = atomicAdd(&fr[k], 1);  // LDS atomic
        etmp[pos] = make_int2(src | (dl << 18), __float_as_int(w));
    }
}

// ---------------------------------------------------------------------------
// K4: exact row placement + row_ptr construction (round-2-proven body).
// Bucket bases re-derived from btot in LDS. LDS atomics only; writes stay
// inside the bucket's 64KB window.
// Output record: x = src*128 (byte offset into fp16 table), y = w bits.
// ---------------------------------------------------------------------------
__global__ __launch_bounds__(256) void place_kernel(
    const int2* __restrict__ etmp, const int* __restrict__ btot,
    int2* __restrict__ edges, int* __restrict__ row_ptr)
{
    __shared__ int sb[512];
    __shared__ int part[256];
    __shared__ int cnt[512];
    __shared__ int cur[512];
    const int k = blockIdx.x;
    const int t = threadIdx.x;
    for (int j = t; j < 512; j += 256) sb[j] = (j < KB_) ? btot[j] : 0;
    __syncthreads();
    {
        const int c0 = sb[2 * t], c1 = sb[2 * t + 1];
        const int run = c0 + c1;
        part[t] = run; __syncthreads();
        for (int off = 1; off < 256; off <<= 1) {
            int add = (t >= off) ? part[t - off] : 0;
            __syncthreads();
            part[t] += add;
            __syncthreads();
        }
        const int base = part[t] - run;
        sb[2 * t]     = base;
        sb[2 * t + 1] = base + c0;
    }
    __syncthreads();
    const int beg = sb[k];
    const int end = (k == KB_ - 1) ? EE : sb[k + 1];
    cnt[t] = 0; cnt[t + 256] = 0;
    __syncthreads();
    for (int e = beg + t; e < end; e += 256)
        atomicAdd(&cnt[((unsigned)etmp[e].x) >> 18], 1);
    __syncthreads();
    const int c0 = cnt[2 * t], c1 = cnt[2 * t + 1];
    const int run = c0 + c1;
    part[t] = run; __syncthreads();
    for (int off = 1; off < 256; off <<= 1) {
        int add = (t >= off) ? part[t - off] : 0;
        __syncthreads();
        part[t] += add;
        __syncthreads();
    }
    const int base = beg + part[t] - run;      // exclusive prefix + bucket base
    cur[2 * t]     = base;
    cur[2 * t + 1] = base + c0;
    const int node0 = (k << 9) + 2 * t;
    if (node0 < NN)     row_ptr[node0]     = base;
    if (node0 + 1 < NN) row_ptr[node0 + 1] = base + c0;
    if (k == KB_ - 1 && t == 0) row_ptr[NN] = EE;
    __syncthreads();
    for (int e = beg + t; e < end; e += 256) {
        const int2 r  = etmp[e];
        const int  dl = ((unsigned)r.x) >> 18;
        const int  pos = atomicAdd(&cur[dl], 1);  // LDS atomic
        edges[pos] = make_int2((r.x & 0x3FFFF) << 7, r.y);   // src byte-offset
    }
}

// ---------------------------------------------------------------------------
// Aggregation (v3, proven 73.5 us): one wave per FOUR adjacent rows,
// lane d = dim d. 4 independent streams x 4-edge unroll -> 16 gathers in
// flight. Row bounds via readfirstlane -> records are scalar s_loads.
// All loads plain cached.
// ---------------------------------------------------------------------------
__global__ __launch_bounds__(256) void aggregate_kernel(
    const int2* __restrict__ edges, const int* __restrict__ row_ptr,
    const _Float16* __restrict__ xh, _Float16* __restrict__ u)
{
    const int wave = (blockIdx.x * 256 + threadIdx.x) >> 6;  // 0..49999
    const int lane = threadIdx.x & 63;
    const unsigned lane2 = lane * 2;
    const int nbase = wave * 4;
    const char* xb = (const char*)xh;

    int bnd[5];
#pragma unroll
    for (int k = 0; k < 5; ++k)
        bnd[k] = __builtin_amdgcn_readfirstlane(row_ptr[nbase + k]);

    float acc[4];
#pragma unroll
    for (int k = 0; k < 4; ++k)
        acc[k] = (float)*(const _Float16*)(xb + ((unsigned)(nbase + k) << 7) + lane2);

    int e0 = bnd[0], e1 = bnd[1], e2 = bnd[2], e3 = bnd[3];
    const int f0 = bnd[1], f1 = bnd[2], f2 = bnd[3], f3 = bnd[4];

    // ---- steady state: 16 gathers in flight from 4 independent streams ----
    while ((e0 + 4 <= f0) && (e1 + 4 <= f1) && (e2 + 4 <= f2) && (e3 + 4 <= f3)) {
        const int2 a0 = edges[e0 + 0], a1 = edges[e0 + 1];
        const int2 a2 = edges[e0 + 2], a3 = edges[e0 + 3];
        const int2 b0 = edges[e1 + 0], b1 = edges[e1 + 1];
        const int2 b2 = edges[e1 + 2], b3 = edges[e1 + 3];
        const int2 c0 = edges[e2 + 0], c1 = edges[e2 + 1];
        const int2 c2 = edges[e2 + 2], c3 = edges[e2 + 3];
        const int2 d0 = edges[e3 + 0], d1 = edges[e3 + 1];
        const int2 d2 = edges[e3 + 2], d3 = edges[e3 + 3];

        const float va0 = (float)*(const _Float16*)(xb + (unsigned)a0.x + lane2);
        const float va1 = (float)*(const _Float16*)(xb + (unsigned)a1.x + lane2);
        const float va2 = (float)*(const _Float16*)(xb + (unsigned)a2.x + lane2);
        const float va3 = (float)*(const _Float16*)(xb + (unsigned)a3.x + lane2);
        const float vb0 = (float)*(const _Float16*)(xb + (unsigned)b0.x + lane2);
        const float vb1 = (float)*(const _Float16*)(xb + (unsigned)b1.x + lane2);
        const float vb2 = (float)*(const _Float16*)(xb + (unsigned)b2.x + lane2);
        const float vb3 = (float)*(const _Float16*)(xb + (unsigned)b3.x + lane2);
        const float vc0 = (float)*(const _Float16*)(xb + (unsigned)c0.x + lane2);
        const float vc1 = (float)*(const _Float16*)(xb + (unsigned)c1.x + lane2);
        const float vc2 = (float)*(const _Float16*)(xb + (unsigned)c2.x + lane2);
        const float vc3 = (float)*(const _Float16*)(xb + (unsigned)c3.x + lane2);
        const float vd0 = (float)*(const _Float16*)(xb + (unsigned)d0.x + lane2);
        const float vd1 = (float)*(const _Float16*)(xb + (unsigned)d1.x + lane2);
        const float vd2 = (float)*(const _Float16*)(xb + (unsigned)d2.x + lane2);
        const float vd3 = (float)*(const _Float16*)(xb + (unsigned)d3.x + lane2);

        acc[0] = fmaf(__int_as_float(a0.y), va0, acc[0]);
        acc[0] = fmaf(__int_as_float(a1.y), va1, acc[0]);
        acc[0] = fmaf(__int_as_float(a2.y), va2, acc[0]);
        acc[0] = fmaf(__int_as_float(a3.y), va3, acc[0]);
        acc[1] = fmaf(__int_as_float(b0.y), vb0, acc[1]);
        acc[1] = fmaf(__int_as_float(b1.y), vb1, acc[1]);
        acc[1] = fmaf(__int_as_float(b2.y), vb2, acc[1]);
        acc[1] = fmaf(__int_as_float(b3.y), vb3, acc[1]);
        acc[2] = fmaf(__int_as_float(c0.y), vc0, acc[2]);
        acc[2] = fmaf(__int_as_float(c1.y), vc1, acc[2]);
        acc[2] = fmaf(__int_as_float(c2.y), vc2, acc[2]);
        acc[2] = fmaf(__int_as_float(c3.y), vc3, acc[2]);
        acc[3] = fmaf(__int_as_float(d0.y), vd0, acc[3]);
        acc[3] = fmaf(__int_as_float(d1.y), vd1, acc[3]);
        acc[3] = fmaf(__int_as_float(d2.y), vd2, acc[3]);
        acc[3] = fmaf(__int_as_float(d3.y), vd3, acc[3]);

        e0 += 4; e1 += 4; e2 += 4; e3 += 4;
    }

    // ---- per-stream drains (4-unroll then scalar) ----
    {
        int e = e0;
        for (; e + 4 <= f0; e += 4) {
            const int2 r0 = edges[e + 0], r1 = edges[e + 1];
            const int2 r2 = edges[e + 2], r3 = edges[e + 3];
            const float v0 = (float)*(const _Float16*)(xb + (unsigned)r0.x + lane2);
            const float v1 = (float)*(const _Float16*)(xb + (unsigned)r1.x + lane2);
            const float v2 = (float)*(const _Float16*)(xb + (unsigned)r2.x + lane2);
            const float v3 = (float)*(const _Float16*)(xb + (unsigned)r3.x + lane2);
            acc[0] = fmaf(__int_as_float(r0.y), v0, acc[0]);
            acc[0] = fmaf(__int_as_float(r1.y), v1, acc[0]);
            acc[0] = fmaf(__int_as_float(r2.y), v2, acc[0]);
            acc[0] = fmaf(__int_as_float(r3.y), v3, acc[0]);
        }
        for (; e < f0; ++e) {
            const int2 p = edges[e];
            acc[0] = fmaf(__int_as_float(p.y),
                          (float)*(const _Float16*)(xb + (unsigned)p.x + lane2), acc[0]);
        }
    }
    {
        int e = e1;
        for (; e + 4 <= f1; e += 4) {
            const int2 r0 = edges[e + 0], r1 = edges[e + 1];
            const int2 r2 = edges[e + 2], r3 = edges[e + 3];
            const float v0 = (float)*(const _Float16*)(xb + (unsigned)r0.x + lane2);
            const float v1 = (float)*(const _Float16*)(xb + (unsigned)r1.x + lane2);
            const float v2 = (float)*(const _Float16*)(xb + (unsigned)r2.x + lane2);
            const float v3 = (float)*(const _Float16*)(xb + (unsigned)r3.x + lane2);
            acc[1] = fmaf(__int_as_float(r0.y), v0, acc[1]);
            acc[1] = fmaf(__int_as_float(r1.y), v1, acc[1]);
            acc[1] = fmaf(__int_as_float(r2.y), v2, acc[1]);
            acc[1] = fmaf(__int_as_float(r3.y), v3, acc[1]);
        }
        for (; e < f1; ++e) {
            const int2 p = edges[e];
            acc[1] = fmaf(__int_as_float(p.y),
                          (float)*(const _Float16*)(xb + (unsigned)p.x + lane2), acc[1]);
        }
    }
    {
        int e = e2;
        for (; e + 4 <= f2; e += 4) {
            const int2 r0 = edges[e + 0], r1 = edges[e + 1];
            const int2 r2 = edges[e + 2], r3 = edges[e + 3];
            const float v0 = (float)*(const _Float16*)(xb + (unsigned)r0.x + lane2);
            const float v1 = (float)*(const _Float16*)(xb + (unsigned)r1.x + lane2);
            const float v2 = (float)*(const _Float16*)(xb + (unsigned)r2.x + lane2);
            const float v3 = (float)*(const _Float16*)(xb + (unsigned)r3.x + lane2);
            acc[2] = fmaf(__int_as_float(r0.y), v0, acc[2]);
            acc[2] = fmaf(__int_as_float(r1.y), v1, acc[2]);
            acc[2] = fmaf(__int_as_float(r2.y), v2, acc[2]);
            acc[2] = fmaf(__int_as_float(r3.y), v3, acc[2]);
        }
        for (; e < f2; ++e) {
            const int2 p = edges[e];
            acc[2] = fmaf(__int_as_float(p.y),
                          (float)*(const _Float16*)(xb + (unsigned)p.x + lane2), acc[2]);
        }
    }
    {
        int e = e3;
        for (; e + 4 <= f3; e += 4) {
            const int2 r0 = edges[e + 0], r1 = edges[e + 1];
            const int2 r2 = edges[e + 2], r3 = edges[e + 3];
            const float v0 = (float)*(const _Float16*)(xb + (unsigned)r0.x + lane2);
            const float v1 = (float)*(const _Float16*)(xb + (unsigned)r1.x + lane2);
            const float v2 = (float)*(const _Float16*)(xb + (unsigned)r2.x + lane2);
            const float v3 = (float)*(const _Float16*)(xb + (unsigned)r3.x + lane2);
            acc[3] = fmaf(__int_as_float(r0.y), v0, acc[3]);
            acc[3] = fmaf(__int_as_float(r1.y), v1, acc[3]);
            acc[3] = fmaf(__int_as_float(r2.y), v2, acc[3]);
            acc[3] = fmaf(__int_as_float(r3.y), v3, acc[3]);
        }
        for (; e < f3; ++e) {
            const int2 p = edges[e];
            acc[3] = fmaf(__int_as_float(p.y),
                          (float)*(const _Float16*)(xb + (unsigned)p.x + lane2), acc[3]);
        }
    }

    char* ub = (char*)u;
#pragma unroll
    for (int k = 0; k < 4; ++k)
        *(_Float16*)(ub + ((unsigned)(nbase + k) << 7) + lane2) = (_Float16)(acc[k] * 0.5f);
}

// ---------------------------------------------------------------------------
// GEMM: out[N,64] = u[N,64] @ W[64,64] + b (unchanged)
// ---------------------------------------------------------------------------
template<bool HALF_OUT>
__global__ __launch_bounds__(256) void gemm64_kernel(
    const _Float16* __restrict__ u, const _Float16* __restrict__ Wt,
    const float* __restrict__ bias, void* __restrict__ outp)
{
    const int wid  = blockIdx.x * 4 + (threadIdx.x >> 6);
    const int lane = threadIdx.x & 63;
    const int m    = lane & 15;
    const int quad = lane >> 4;
    const size_t rowbase = (size_t)wid * 16;

    half8 bf[4][2];
#pragma unroll
    for (int c = 0; c < 4; ++c)
#pragma unroll
        for (int h = 0; h < 2; ++h)
            bf[c][h] = *(const half8*)(Wt + (size_t)(c * 16 + m) * DD + h * 32 + quad * 8);

    const half8 a0 = *(const half8*)(u + (rowbase + m) * DD +  0 + quad * 8);
    const half8 a1 = *(const half8*)(u + (rowbase + m) * DD + 32 + quad * 8);

    f32x4 acc[4];
#pragma unroll
    for (int c = 0; c < 4; ++c) {
        f32x4 z = {0.f, 0.f, 0.f, 0.f};
        z = __builtin_amdgcn_mfma_f32_16x16x32_f16(a0, bf[c][0], z, 0, 0, 0);
        z = __builtin_amdgcn_mfma_f32_16x16x32_f16(a1, bf[c][1], z, 0, 0, 0);
        acc[c] = z;
    }

#pragma unroll
    for (int c = 0; c < 4; ++c) {
        const float bv = bias[c * 16 + m];
#pragma unroll
        for (int r = 0; r < 4; ++r) {
            const size_t row = rowbase + quad * 4 + r;
            const float val = acc[c][r] + bv;
            if (HALF_OUT) ((_Float16*)outp)[row * DD + c * 16 + m] = (_Float16)val;
            else          ((float*)    outp)[row * DD + c * 16 + m] = val;
        }
    }
}

extern "C" void kernel_launch(void* const* d_in, const int* in_sizes, int n_in,
                              void* d_out, int out_size, void* d_ws, size_t ws_size,
                              hipStream_t stream) {
    const int*   edge_index  = (const int*)  d_in[0];
    const float* edge_weight = (const float*)d_in[1];
    const float* user_emb    = (const float*)d_in[2];
    const float* item_emb    = (const float*)d_in[3];
    const float* W1          = (const float*)d_in[4];
    const float* b1          = (const float*)d_in[5];
    const float* W2          = (const float*)d_in[6];
    const float* b2          = (const float*)d_in[7];
    float*       out         = (float*)d_out;

    // Workspace layout:
    char* ws = (char*)d_ws;
    _Float16* xh        = (_Float16*)(ws);               // 25,600,000 B (h1 aliases after layer 1)
    _Float16* u         = (_Float16*)(ws + 25600000);    // 25,600,000 B — also etmp during build
    int2*     etmp      = (int2*)    (ws + 25600000);    //   (alias of u)
    int2*     edges     = (int2*)    (ws + 51200000);    // 25,600,000 B (row-grouped)
    int*      row_ptr   = (int*)     (ws + 76800000);    //    800,064 B (NN+1 ints)
    int*      counts_seg= (int*)     (ws + 77600064);    //    800,768 B ([s][k], becomes rel)
    int*      btot      = (int*)     (ws + 78400832);    //      1,600 B
    _Float16* Wt        = (_Float16*)(ws + 78402432);    //     16,384 B

    const int gemm_blocks = (NN / 16) / 4;               // 3125
    const int agg_blocks  = NN / 16;                     // 12500 (4 nodes/wave, 4 waves/block)
    const int prep_blocks = GSEG + CVX_BLOCKS + CVW_BLOCKS;  // 13044

    // ---- build (4 kernels, zero global atomics) + conversions fused ----
    prep_kernel  <<<prep_blocks, 256, 0, stream>>>(edge_index, user_emb, item_emb,
                                                   W1, W2, counts_seg, xh, Wt);
    bscan_kernel <<<KB_,  256, 0, stream>>>(counts_seg, btot);
    append_kernel<<<GSEG, 256, 0, stream>>>(edge_index, edge_weight,
                                            counts_seg, btot, etmp);
    place_kernel <<<KB_,  256, 0, stream>>>(etmp, btot, edges, row_ptr);

    // ---- Layer 1 ----
    aggregate_kernel<<<agg_blocks, 256, 0, stream>>>(edges, row_ptr, xh, u);
    gemm64_kernel<true><<<gemm_blocks, 256, 0, stream>>>(u, Wt, b1, (void*)xh);

    // ---- Layer 2 ----
    aggregate_kernel<<<agg_blocks, 256, 0, stream>>>(edges, row_ptr, xh, u);
    gemm64_kernel<false><<<gemm_blocks, 256, 0, stream>>>(u, Wt + DD * DD, b2, (void*)out);
}

// Round 10
// 415.960 us; speedup vs baseline: 1.4839x; 1.0360x over previous
//
#include <hip/hip_runtime.h>
#include <hip/hip_fp16.h>

#define NUM_USERS 100000
#define NN        200000          // N = users + items
#define DD        64
#define EE        3200000

#define KB_   391                 // dst buckets: 512 nodes each (dst >> 9)
#define GSEG  512                 // edge segments for append
#define EPS   (EE / GSEG)         // 6250 edges per segment
#define CVX_BLOCKS 12500          // NN*DD/4 / 256
#define CVW_BLOCKS 32             // 2*DD*DD / 256

typedef _Float16 half8 __attribute__((ext_vector_type(8)));
typedef _Float16 half4 __attribute__((ext_vector_type(4)));
typedef float    f32x4 __attribute__((ext_vector_type(4)));

// ---------------------------------------------------------------------------
// K1 (fused): seg-histogram (blocks [0,512)) || convert_x || convert_w.
// counts_seg layout [s][k]. No global atomics anywhere in the pipeline.
// ---------------------------------------------------------------------------
__global__ __launch_bounds__(256) void prep_kernel(
    const int* __restrict__ ei,
    const float* __restrict__ xu, const float* __restrict__ xi,
    const float* __restrict__ W1, const float* __restrict__ W2,
    int* __restrict__ counts_seg, _Float16* __restrict__ xh,
    _Float16* __restrict__ Wt)
{
    __shared__ int h[KB_];
    const int b = blockIdx.x;
    const int t = threadIdx.x;
    if (b < GSEG) {
        for (int k = t; k < KB_; k += 256) h[k] = 0;
        __syncthreads();
        const int base = b * EPS;
        for (int i = t; i < EPS; i += 256) {
            const int dst = ei[EE + base + i];
            atomicAdd(&h[dst >> 9], 1);        // LDS atomic
        }
        __syncthreads();
        for (int k = t; k < KB_; k += 256)
            counts_seg[b * KB_ + k] = h[k];
    } else if (b < GSEG + CVX_BLOCKS) {
        const int i = (b - GSEG) * 256 + t;    // < NN*DD/4
        const float4 v = (i < NUM_USERS * DD / 4)
                           ? ((const float4*)xu)[i]
                           : ((const float4*)xi)[i - NUM_USERS * DD / 4];
        half4 o; o[0] = (_Float16)v.x; o[1] = (_Float16)v.y;
                 o[2] = (_Float16)v.z; o[3] = (_Float16)v.w;
        ((half4*)xh)[i] = o;
    } else {
        const int idx = (b - GSEG - CVX_BLOCKS) * 256 + t;   // < 2*DD*DD
        const int mat = idx >> 12, rem = idx & 4095, k = rem >> 6, n = rem & 63;
        const float* W = mat ? W2 : W1;
        Wt[mat * DD * DD + n * DD + k] = (_Float16)W[k * DD + n];
    }
}

// ---------------------------------------------------------------------------
// K2: per-bucket exclusive scan across the 512 segments (in place) + btot.
// ---------------------------------------------------------------------------
__global__ __launch_bounds__(256) void bscan_kernel(
    int* __restrict__ counts_seg, int* __restrict__ btot)
{
    __shared__ int part[256];
    const int k = blockIdx.x;
    const int t = threadIdx.x;
    const int c0 = counts_seg[(2 * t)     * KB_ + k];
    const int c1 = counts_seg[(2 * t + 1) * KB_ + k];
    const int run = c0 + c1;
    part[t] = run; __syncthreads();
    for (int off = 1; off < 256; off <<= 1) {
        int add = (t >= off) ? part[t - off] : 0;
        __syncthreads();
        part[t] += add;
        __syncthreads();
    }
    const int base = part[t] - run;            // exclusive within bucket
    counts_seg[(2 * t)     * KB_ + k] = base;
    counts_seg[(2 * t + 1) * KB_ + k] = base + c0;
    if (t == 255) btot[k] = part[255];
}

// ---------------------------------------------------------------------------
// K3: append into bucket-grouped etmp. Bucket bases derived in-block by
// scanning btot in LDS; frontier = base + rel[s][k]. LDS atomics only.
// Record: x = src | dst_local<<18, y = w bits.
// ---------------------------------------------------------------------------
__global__ __launch_bounds__(256) void append_kernel(
    const int* __restrict__ ei, const float* __restrict__ ew,
    const int* __restrict__ counts_seg, const int* __restrict__ btot,
    int2* __restrict__ etmp)
{
    __shared__ int sb[512];
    __shared__ int part[256];
    __shared__ int fr[KB_];
    const int s = blockIdx.x;
    const int t = threadIdx.x;
    for (int j = t; j < 512; j += 256) sb[j] = (j < KB_) ? btot[j] : 0;
    __syncthreads();
    {
        const int c0 = sb[2 * t], c1 = sb[2 * t + 1];
        const int run = c0 + c1;
        part[t] = run; __syncthreads();
        for (int off = 1; off < 256; off <<= 1) {
            int add = (t >= off) ? part[t - off] : 0;
            __syncthreads();
            part[t] += add;
            __syncthreads();
        }
        const int base = part[t] - run;
        sb[2 * t]     = base;                  // exclusive bucket bases
        sb[2 * t + 1] = base + c0;
    }
    __syncthreads();
    for (int k = t; k < KB_; k += 256)
        fr[k] = sb[k] + counts_seg[s * KB_ + k];
    __syncthreads();
    const int base = s * EPS;
    for (int i = t; i < EPS; i += 256) {
        const int e   = base + i;
        const int   src = ei[e];
        const int   dst = ei[EE + e];
        const float w   = ew[e];
        const int k  = dst >> 9;
        const int dl = dst & 511;
        const int pos = atomicAdd(&fr[k], 1);  // LDS atomic
        etmp[pos] = make_int2(src | (dl << 18), __float_as_int(w));
    }
}

// ---------------------------------------------------------------------------
// K4: exact row placement + row_ptr construction. LDS atomics only; writes
// stay inside the bucket's 64KB window.
// Output record: x = src*128 (byte offset into fp16 table), y = w bits.
// ---------------------------------------------------------------------------
__global__ __launch_bounds__(256) void place_kernel(
    const int2* __restrict__ etmp, const int* __restrict__ btot,
    int2* __restrict__ edges, int* __restrict__ row_ptr)
{
    __shared__ int sb[512];
    __shared__ int part[256];
    __shared__ int cnt[512];
    __shared__ int cur[512];
    const int k = blockIdx.x;
    const int t = threadIdx.x;
    for (int j = t; j < 512; j += 256) sb[j] = (j < KB_) ? btot[j] : 0;
    __syncthreads();
    {
        const int c0 = sb[2 * t], c1 = sb[2 * t + 1];
        const int run = c0 + c1;
        part[t] = run; __syncthreads();
        for (int off = 1; off < 256; off <<= 1) {
            int add = (t >= off) ? part[t - off] : 0;
            __syncthreads();
            part[t] += add;
            __syncthreads();
        }
        const int base = part[t] - run;
        sb[2 * t]     = base;
        sb[2 * t + 1] = base + c0;
    }
    __syncthreads();
    const int beg = sb[k];
    const int end = (k == KB_ - 1) ? EE : sb[k + 1];
    cnt[t] = 0; cnt[t + 256] = 0;
    __syncthreads();
    for (int e = beg + t; e < end; e += 256)
        atomicAdd(&cnt[((unsigned)etmp[e].x) >> 18], 1);
    __syncthreads();
    const int c0 = cnt[2 * t], c1 = cnt[2 * t + 1];
    const int run = c0 + c1;
    part[t] = run; __syncthreads();
    for (int off = 1; off < 256; off <<= 1) {
        int add = (t >= off) ? part[t - off] : 0;
        __syncthreads();
        part[t] += add;
        __syncthreads();
    }
    const int base = beg + part[t] - run;      // exclusive prefix + bucket base
    cur[2 * t]     = base;
    cur[2 * t + 1] = base + c0;
    const int node0 = (k << 9) + 2 * t;
    if (node0 < NN)     row_ptr[node0]     = base;
    if (node0 + 1 < NN) row_ptr[node0 + 1] = base + c0;
    if (k == KB_ - 1 && t == 0) row_ptr[NN] = EE;
    __syncthreads();
    for (int e = beg + t; e < end; e += 256) {
        const int2 r  = etmp[e];
        const int  dl = ((unsigned)r.x) >> 18;
        const int  pos = atomicAdd(&cur[dl], 1);  // LDS atomic
        edges[pos] = make_int2((r.x & 0x3FFFF) << 7, r.y);   // src byte-offset
    }
}

// ---------------------------------------------------------------------------
// FUSED aggregate + GEMM. Block = 4 waves x 4 rows = 16 rows = one MFMA
// M=16 tile. Aggregate body is the proven v3 (16 gathers in flight, scalar
// records). Epilogue: scaled rows -> LDS ut[16][72] (144B stride = 9x16B,
// so half8 loads stay 16B-aligned), then wave w computes output col-block
// c=w with 2 MFMAs (gemm64 fragment math), adds bias, writes out.
// Removes the u round-trip and 2 dispatches.
// ---------------------------------------------------------------------------
template<bool HALF_OUT>
__global__ __launch_bounds__(256) void agg_gemm_kernel(
    const int2* __restrict__ edges, const int* __restrict__ row_ptr,
    const _Float16* __restrict__ xh, const _Float16* __restrict__ Wt,
    const float* __restrict__ bias, void* __restrict__ outp)
{
    __shared__ _Float16 ut[16][72];   // stride 72: 16B-aligned rows
    const int t    = threadIdx.x;
    const int w    = t >> 6;          // wave 0..3
    const int lane = t & 63;
    const unsigned lane2 = lane * 2;
    const int nbase = blockIdx.x * 16 + w * 4;
    const char* xb = (const char*)xh;

    int bnd[5];
#pragma unroll
    for (int k = 0; k < 5; ++k)
        bnd[k] = __builtin_amdgcn_readfirstlane(row_ptr[nbase + k]);

    float acc[4];
#pragma unroll
    for (int k = 0; k < 4; ++k)
        acc[k] = (float)*(const _Float16*)(xb + ((unsigned)(nbase + k) << 7) + lane2);

    int e0 = bnd[0], e1 = bnd[1], e2 = bnd[2], e3 = bnd[3];
    const int f0 = bnd[1], f1 = bnd[2], f2 = bnd[3], f3 = bnd[4];

    // ---- steady state: 16 gathers in flight from 4 independent streams ----
    while ((e0 + 4 <= f0) && (e1 + 4 <= f1) && (e2 + 4 <= f2) && (e3 + 4 <= f3)) {
        const int2 a0 = edges[e0 + 0], a1 = edges[e0 + 1];
        const int2 a2 = edges[e0 + 2], a3 = edges[e0 + 3];
        const int2 b0 = edges[e1 + 0], b1 = edges[e1 + 1];
        const int2 b2 = edges[e1 + 2], b3 = edges[e1 + 3];
        const int2 c0 = edges[e2 + 0], c1 = edges[e2 + 1];
        const int2 c2 = edges[e2 + 2], c3 = edges[e2 + 3];
        const int2 d0 = edges[e3 + 0], d1 = edges[e3 + 1];
        const int2 d2 = edges[e3 + 2], d3 = edges[e3 + 3];

        const float va0 = (float)*(const _Float16*)(xb + (unsigned)a0.x + lane2);
        const float va1 = (float)*(const _Float16*)(xb + (unsigned)a1.x + lane2);
        const float va2 = (float)*(const _Float16*)(xb + (unsigned)a2.x + lane2);
        const float va3 = (float)*(const _Float16*)(xb + (unsigned)a3.x + lane2);
        const float vb0 = (float)*(const _Float16*)(xb + (unsigned)b0.x + lane2);
        const float vb1 = (float)*(const _Float16*)(xb + (unsigned)b1.x + lane2);
        const float vb2 = (float)*(const _Float16*)(xb + (unsigned)b2.x + lane2);
        const float vb3 = (float)*(const _Float16*)(xb + (unsigned)b3.x + lane2);
        const float vc0 = (float)*(const _Float16*)(xb + (unsigned)c0.x + lane2);
        const float vc1 = (float)*(const _Float16*)(xb + (unsigned)c1.x + lane2);
        const float vc2 = (float)*(const _Float16*)(xb + (unsigned)c2.x + lane2);
        const float vc3 = (float)*(const _Float16*)(xb + (unsigned)c3.x + lane2);
        const float vd0 = (float)*(const _Float16*)(xb + (unsigned)d0.x + lane2);
        const float vd1 = (float)*(const _Float16*)(xb + (unsigned)d1.x + lane2);
        const float vd2 = (float)*(const _Float16*)(xb + (unsigned)d2.x + lane2);
        const float vd3 = (float)*(const _Float16*)(xb + (unsigned)d3.x + lane2);

        acc[0] = fmaf(__int_as_float(a0.y), va0, acc[0]);
        acc[0] = fmaf(__int_as_float(a1.y), va1, acc[0]);
        acc[0] = fmaf(__int_as_float(a2.y), va2, acc[0]);
        acc[0] = fmaf(__int_as_float(a3.y), va3, acc[0]);
        acc[1] = fmaf(__int_as_float(b0.y), vb0, acc[1]);
        acc[1] = fmaf(__int_as_float(b1.y), vb1, acc[1]);
        acc[1] = fmaf(__int_as_float(b2.y), vb2, acc[1]);
        acc[1] = fmaf(__int_as_float(b3.y), vb3, acc[1]);
        acc[2] = fmaf(__int_as_float(c0.y), vc0, acc[2]);
        acc[2] = fmaf(__int_as_float(c1.y), vc1, acc[2]);
        acc[2] = fmaf(__int_as_float(c2.y), vc2, acc[2]);
        acc[2] = fmaf(__int_as_float(c3.y), vc3, acc[2]);
        acc[3] = fmaf(__int_as_float(d0.y), vd0, acc[3]);
        acc[3] = fmaf(__int_as_float(d1.y), vd1, acc[3]);
        acc[3] = fmaf(__int_as_float(d2.y), vd2, acc[3]);
        acc[3] = fmaf(__int_as_float(d3.y), vd3, acc[3]);

        e0 += 4; e1 += 4; e2 += 4; e3 += 4;
    }

    // ---- per-stream drains (4-unroll then scalar) ----
    {
        int e = e0;
        for (; e + 4 <= f0; e += 4) {
            const int2 r0 = edges[e + 0], r1 = edges[e + 1];
            const int2 r2 = edges[e + 2], r3 = edges[e + 3];
            const float v0 = (float)*(const _Float16*)(xb + (unsigned)r0.x + lane2);
            const float v1 = (float)*(const _Float16*)(xb + (unsigned)r1.x + lane2);
            const float v2 = (float)*(const _Float16*)(xb + (unsigned)r2.x + lane2);
            const float v3 = (float)*(const _Float16*)(xb + (unsigned)r3.x + lane2);
            acc[0] = fmaf(__int_as_float(r0.y), v0, acc[0]);
            acc[0] = fmaf(__int_as_float(r1.y), v1, acc[0]);
            acc[0] = fmaf(__int_as_float(r2.y), v2, acc[0]);
            acc[0] = fmaf(__int_as_float(r3.y), v3, acc[0]);
        }
        for (; e < f0; ++e) {
            const int2 p = edges[e];
            acc[0] = fmaf(__int_as_float(p.y),
                          (float)*(const _Float16*)(xb + (unsigned)p.x + lane2), acc[0]);
        }
    }
    {
        int e = e1;
        for (; e + 4 <= f1; e += 4) {
            const int2 r0 = edges[e + 0], r1 = edges[e + 1];
            const int2 r2 = edges[e + 2], r3 = edges[e + 3];
            const float v0 = (float)*(const _Float16*)(xb + (unsigned)r0.x + lane2);
            const float v1 = (float)*(const _Float16*)(xb + (unsigned)r1.x + lane2);
            const float v2 = (float)*(const _Float16*)(xb + (unsigned)r2.x + lane2);
            const float v3 = (float)*(const _Float16*)(xb + (unsigned)r3.x + lane2);
            acc[1] = fmaf(__int_as_float(r0.y), v0, acc[1]);
            acc[1] = fmaf(__int_as_float(r1.y), v1, acc[1]);
            acc[1] = fmaf(__int_as_float(r2.y), v2, acc[1]);
            acc[1] = fmaf(__int_as_float(r3.y), v3, acc[1]);
        }
        for (; e < f1; ++e) {
            const int2 p = edges[e];
            acc[1] = fmaf(__int_as_float(p.y),
                          (float)*(const _Float16*)(xb + (unsigned)p.x + lane2), acc[1]);
        }
    }
    {
        int e = e2;
        for (; e + 4 <= f2; e += 4) {
            const int2 r0 = edges[e + 0], r1 = edges[e + 1];
            const int2 r2 = edges[e + 2], r3 = edges[e + 3];
            const float v0 = (float)*(const _Float16*)(xb + (unsigned)r0.x + lane2);
            const float v1 = (float)*(const _Float16*)(xb + (unsigned)r1.x + lane2);
            const float v2 = (float)*(const _Float16*)(xb + (unsigned)r2.x + lane2);
            const float v3 = (float)*(const _Float16*)(xb + (unsigned)r3.x + lane2);
            acc[2] = fmaf(__int_as_float(r0.y), v0, acc[2]);
            acc[2] = fmaf(__int_as_float(r1.y), v1, acc[2]);
            acc[2] = fmaf(__int_as_float(r2.y), v2, acc[2]);
            acc[2] = fmaf(__int_as_float(r3.y), v3, acc[2]);
        }
        for (; e < f2; ++e) {
            const int2 p = edges[e];
            acc[2] = fmaf(__int_as_float(p.y),
                          (float)*(const _Float16*)(xb + (unsigned)p.x + lane2), acc[2]);
        }
    }
    {
        int e = e3;
        for (; e + 4 <= f3; e += 4) {
            const int2 r0 = edges[e + 0], r1 = edges[e + 1];
            const int2 r2 = edges[e + 2], r3 = edges[e + 3];
            const float v0 = (float)*(const _Float16*)(xb + (unsigned)r0.x + lane2);
            const float v1 = (float)*(const _Float16*)(xb + (unsigned)r1.x + lane2);
            const float v2 = (float)*(const _Float16*)(xb + (unsigned)r2.x + lane2);
            const float v3 = (float)*(const _Float16*)(xb + (unsigned)r3.x + lane2);
            acc[3] = fmaf(__int_as_float(r0.y), v0, acc[3]);
            acc[3] = fmaf(__int_as_float(r1.y), v1, acc[3]);
            acc[3] = fmaf(__int_as_float(r2.y), v2, acc[3]);
            acc[3] = fmaf(__int_as_float(r3.y), v3, acc[3]);
        }
        for (; e < f3; ++e) {
            const int2 p = edges[e];
            acc[3] = fmaf(__int_as_float(p.y),
                          (float)*(const _Float16*)(xb + (unsigned)p.x + lane2), acc[3]);
        }
    }

    // ---- epilogue: scaled rows -> LDS, then per-wave MFMA col-block ----
#pragma unroll
    for (int k = 0; k < 4; ++k)
        ut[(w << 2) + k][lane] = (_Float16)(acc[k] * 0.5f);
    __syncthreads();

    const int m    = lane & 15;
    const int quad = lane >> 4;
    const half8 a0 = *(const half8*)(&ut[m][ 0 + quad * 8]);
    const half8 a1 = *(const half8*)(&ut[m][32 + quad * 8]);
    const half8 w0 = *(const half8*)(Wt + (size_t)(w * 16 + m) * DD +  0 + quad * 8);
    const half8 w1 = *(const half8*)(Wt + (size_t)(w * 16 + m) * DD + 32 + quad * 8);
    f32x4 z = {0.f, 0.f, 0.f, 0.f};
    z = __builtin_amdgcn_mfma_f32_16x16x32_f16(a0, w0, z, 0, 0, 0);
    z = __builtin_amdgcn_mfma_f32_16x16x32_f16(a1, w1, z, 0, 0, 0);
    const float bv = bias[w * 16 + m];
    const int rowb = blockIdx.x * 16;
#pragma unroll
    for (int r = 0; r < 4; ++r) {
        const int row = rowb + quad * 4 + r;
        const float val = z[r] + bv;
        if (HALF_OUT) ((_Float16*)outp)[row * DD + w * 16 + m] = (_Float16)val;
        else          ((float*)    outp)[row * DD + w * 16 + m] = val;
    }
}

extern "C" void kernel_launch(void* const* d_in, const int* in_sizes, int n_in,
                              void* d_out, int out_size, void* d_ws, size_t ws_size,
                              hipStream_t stream) {
    const int*   edge_index  = (const int*)  d_in[0];
    const float* edge_weight = (const float*)d_in[1];
    const float* user_emb    = (const float*)d_in[2];
    const float* item_emb    = (const float*)d_in[3];
    const float* W1          = (const float*)d_in[4];
    const float* b1          = (const float*)d_in[5];
    const float* W2          = (const float*)d_in[6];
    const float* b2          = (const float*)d_in[7];
    float*       out         = (float*)d_out;

    // Workspace layout:
    char* ws = (char*)d_ws;
    _Float16* xh        = (_Float16*)(ws);               // 25,600,000 B (layer-1 input table)
    _Float16* uh        = (_Float16*)(ws + 25600000);    // 25,600,000 B (h1 table) — aliases etmp
    int2*     etmp      = (int2*)    (ws + 25600000);    //   (alias of uh; dead after place)
    int2*     edges     = (int2*)    (ws + 51200000);    // 25,600,000 B (row-grouped)
    int*      row_ptr   = (int*)     (ws + 76800000);    //    800,064 B (NN+1 ints)
    int*      counts_seg= (int*)     (ws + 77600064);    //    800,768 B ([s][k], becomes rel)
    int*      btot      = (int*)     (ws + 78400832);    //      1,600 B
    _Float16* Wt        = (_Float16*)(ws + 78402432);    //     16,384 B

    const int agg_blocks  = NN / 16;                     // 12500 (16 rows/block)
    const int prep_blocks = GSEG + CVX_BLOCKS + CVW_BLOCKS;  // 13044

    // ---- build (4 kernels, zero global atomics) + conversions fused ----
    prep_kernel  <<<prep_blocks, 256, 0, stream>>>(edge_index, user_emb, item_emb,
                                                   W1, W2, counts_seg, xh, Wt);
    bscan_kernel <<<KB_,  256, 0, stream>>>(counts_seg, btot);
    append_kernel<<<GSEG, 256, 0, stream>>>(edge_index, edge_weight,
                                            counts_seg, btot, etmp);
    place_kernel <<<KB_,  256, 0, stream>>>(etmp, btot, edges, row_ptr);

    // ---- Layer 1 (fused aggregate+GEMM): xh -> uh ----
    agg_gemm_kernel<true ><<<agg_blocks, 256, 0, stream>>>(edges, row_ptr, xh,
                                                           Wt, b1, (void*)uh);
    // ---- Layer 2 (fused aggregate+GEMM): uh -> out ----
    agg_gemm_kernel<false><<<agg_blocks, 256, 0, stream>>>(edges, row_ptr, uh,
                                                           Wt + DD * DD, b2, (void*)out);
}